// Round 5
// baseline (364.673 us; speedup 1.0000x reference)
//
#include <hip/hip_runtime.h>
#include <hip/hip_bf16.h>

// CrossAttention: B=4, C=256, N=4096, OUT=256, temp=16.
// v5: barrier-free, staging-free flash.
//  - qkv_proj writes K/V in MFMA-fragment-tiled layouts:
//      kt[b][mt16][ko8][m16][32 shorts]  (S-phase A-frags = dense 1KB/wave b128)
//      vt[b][mt32][o256][32 shorts]      (PV  A-frags = dense 1KB/wave b128)
//    so flash loads fragments global->VGPR via L1/L2 (4 waves share lines).
//  - flash has NO __syncthreads, no K/V staging; only wave-private P LDS
//    round-trip (10.2 KB) with same-wave lgkmcnt ordering (proven in r4).
//  - XCD swizzle: bz = (blockIdx.x%8)>>1 so each XCD's L2 caches one K/V chunk.
//  - No-max softmax (|logit|<=~2.5) => split-m partials are sums, atomicAdd.
// Workspace: qg 8.4MB + kt 8.4MB + vt 8.4MB + lp 64KB + wb 384KB.

typedef __attribute__((ext_vector_type(8))) short bf16x8;
typedef __attribute__((ext_vector_type(4))) float f32x4;
typedef __attribute__((ext_vector_type(4))) short short4t;

constexpr int B_ = 4;
constexpr int C_ = 256;
constexpr int N_ = 4096;
constexpr int O_ = 256;
constexpr float INV_TEMP = 1.0f / 16.0f;
constexpr int SPLIT = 4;
constexpr int MCHUNK = N_ / SPLIT;   // 1024 keys per WG

__device__ __forceinline__ short f2bf(float f) {
  union { float f; unsigned u; } v; v.f = f;
  unsigned r = v.u + 0x7fffu + ((v.u >> 16) & 1u);   // RNE
  return (short)(r >> 16);
}

// ---------------------------------------------------------------------------
__global__ void wcvt(const float* __restrict__ Wq, const float* __restrict__ Wk,
                     const float* __restrict__ Wv, short* __restrict__ wb) {
  int i = blockIdx.x * 256 + threadIdx.x;        // 0..196607
  int mat = i >> 16, off = i & 65535;
  const float* W = (mat == 0) ? Wq : (mat == 1 ? Wk : Wv);
  wb[i] = f2bf(W[off]);
}

__global__ void zero_k(float4* __restrict__ out4, float4* __restrict__ lp4) {
  int i = blockIdx.x * 256 + threadIdx.x;        // 0..1052671
  if (i < 1048576) out4[i] = (float4){0.f, 0.f, 0.f, 0.f};
  else lp4[i - 1048576] = (float4){0.f, 0.f, 0.f, 0.f};
}

__global__ void norm_k(float* __restrict__ out, const float* __restrict__ lp) {
  int i = blockIdx.x * 256 + threadIdx.x;        // float4 index
  int e = i * 4;
  int n = e & (N_ - 1);
  int b = e >> 20;                               // 256*4096 floats per batch
  float4 o = ((float4*)out)[i];
  const float4 l = *(const float4*)&lp[(b << 12) + n];
  o.x /= l.x; o.y /= l.y; o.z /= l.z; o.w /= l.w;
  ((float4*)out)[i] = o;
}

// ---------------------------------------------------------------------------
// Projections, LDS-free. Grid (N/64, B, 3). Block 256 (4 waves).
// mat 0: q/16 -> qg[b][n][o]
// mat 1: k    -> kt tiled [b][m>>4][o>>5][m&15][o&31]
// mat 2: v    -> vt tiled [b][m>>5][o][m&31]
// ---------------------------------------------------------------------------
__global__ __launch_bounds__(256, 2) void qkv_proj(
    const float* __restrict__ x, const float* __restrict__ xx,
    const short* __restrict__ wb,
    short* __restrict__ qg, short* __restrict__ kt, short* __restrict__ vt) {
  const int n0  = blockIdx.x * 64;
  const int b   = blockIdx.y;
  const int mat = blockIdx.z;
  const float* src = (mat == 0) ? x : xx;
  const short* W   = wb + mat * 65536;
  const int tid = threadIdx.x;
  const int w = tid >> 6, lane = tid & 63;
  const int g = lane >> 4, c16 = lane & 15;

  f32x4 acc[4][4];
  for (int i = 0; i < 4; ++i)
    for (int j = 0; j < 4; ++j) acc[i][j] = (f32x4){0.f, 0.f, 0.f, 0.f};

  for (int ko = 0; ko < 8; ++ko) {
    bf16x8 afr[4], bfr[4];
#pragma unroll
    for (int ot = 0; ot < 4; ++ot)
      afr[ot] = *(const bf16x8*)&W[(w * 64 + ot * 16 + c16) * C_ + ko * 32 + g * 8];
#pragma unroll
    for (int nt = 0; nt < 4; ++nt) {
      const int n = n0 + nt * 16 + c16;
      const float* sp = src + ((size_t)(b * C_ + ko * 32 + g * 8)) * N_ + n;
      bf16x8 bv;
#pragma unroll
      for (int j = 0; j < 8; ++j) bv[j] = f2bf(sp[(size_t)j * N_]);
      bfr[nt] = bv;
    }
#pragma unroll
    for (int ot = 0; ot < 4; ++ot)
#pragma unroll
      for (int nt = 0; nt < 4; ++nt)
        acc[ot][nt] = __builtin_amdgcn_mfma_f32_16x16x32_bf16(
            afr[ot], bfr[nt], acc[ot][nt], 0, 0, 0);
  }

  if (mat == 0) {
    short* dst = qg + (size_t)b * N_ * O_;
#pragma unroll
    for (int ot = 0; ot < 4; ++ot)
#pragma unroll
      for (int nt = 0; nt < 4; ++nt) {
        int n = n0 + nt * 16 + c16;
        int o = w * 64 + ot * 16 + g * 4;
        short4t s;
        s[0] = f2bf(acc[ot][nt][0] * INV_TEMP);
        s[1] = f2bf(acc[ot][nt][1] * INV_TEMP);
        s[2] = f2bf(acc[ot][nt][2] * INV_TEMP);
        s[3] = f2bf(acc[ot][nt][3] * INV_TEMP);
        *(short4t*)(dst + (size_t)n * O_ + o) = s;
      }
  } else if (mat == 1) {
#pragma unroll
    for (int ot = 0; ot < 4; ++ot)
#pragma unroll
      for (int nt = 0; nt < 4; ++nt) {
        int n = n0 + nt * 16 + c16;       // key index m
        int o = w * 64 + ot * 16 + g * 4;
        size_t base =
            ((((size_t)(b * 256 + (n >> 4)) * 8 + (o >> 5)) * 16 + (n & 15)))
                * 32 + (o & 31);
        short4t s;
        s[0] = f2bf(acc[ot][nt][0]);
        s[1] = f2bf(acc[ot][nt][1]);
        s[2] = f2bf(acc[ot][nt][2]);
        s[3] = f2bf(acc[ot][nt][3]);
        *(short4t*)(kt + base) = s;
      }
  } else {
#pragma unroll
    for (int ot = 0; ot < 4; ++ot)
#pragma unroll
      for (int nt = 0; nt < 4; ++nt) {
        int m = n0 + nt * 16 + c16;       // key index m
        int ob = w * 64 + ot * 16 + g * 4;
#pragma unroll
        for (int r = 0; r < 4; ++r)
          vt[(((size_t)(b * 128 + (m >> 5)) * 256 + ob + r)) * 32 + (m & 31)] =
              f2bf(acc[ot][nt][r]);
      }
  }
}

// ---------------------------------------------------------------------------
// Flash (no-rescale, barrier-free). Grid (32, B, SPLIT). Block 256 (4 waves).
// Wave w owns q-rows [w*32, w*32+32) of a 128-row n-block. Per 32-key iter:
// S^T = K Q^T (16 MFMA, kf direct from kt), exp -> wave-private ps (LDS),
// O += V P^T (32 MFMA, vf direct from vt). XCD swizzle keys chunks to L2.
// ---------------------------------------------------------------------------
__global__ __launch_bounds__(256, 2) void flash_attn(
    const short* __restrict__ qg, const short* __restrict__ kt,
    const short* __restrict__ vt, float* __restrict__ out,
    float* __restrict__ lp) {
  const int xr = blockIdx.x;
  const int b  = blockIdx.y;
  const int bz   = (xr & 7) >> 1;                      // = f(xcd): L2 locality
  const int nblk = (xr >> 3) + ((xr & 1) << 2) + (blockIdx.z << 3);
  const int n0 = nblk * 128;
  const int mbase = bz * MCHUNK;
  const int tid = threadIdx.x;
  const int w = tid >> 6, lane = tid & 63;
  const int g = lane >> 4, c16 = lane & 15;

  __shared__ short ps[128][40];    // P round-trip, wave-private rows (10.2KB)

  // Q fragments: 2 n-subtiles x 8 k-steps (B-operand: col=n, k=o)
  bf16x8 qf[2][8];
#pragma unroll
  for (int nt = 0; nt < 2; ++nt) {
    const short* qrow =
        qg + (size_t)(b * N_ + n0 + w * 32 + nt * 16 + c16) * O_ + g * 8;
#pragma unroll
    for (int ko = 0; ko < 8; ++ko) qf[nt][ko] = *(const bf16x8*)(qrow + ko * 32);
  }

  f32x4 oacc[16][2];
#pragma unroll
  for (int i = 0; i < 16; ++i)
#pragma unroll
    for (int nt = 0; nt < 2; ++nt) oacc[i][nt] = (f32x4){0.f, 0.f, 0.f, 0.f};
  float lrun[2] = {0.f, 0.f};

  const short* ktb = kt + (size_t)b * N_ * O_;
  const short* vtb = vt + (size_t)b * N_ * O_;

  for (int mi = 0; mi < MCHUNK / 32; ++mi) {
    const int mt0 = (mbase >> 4) + mi * 2;   // 16-row K tile index

    // S^T = K Q^T : A = K-frag (row=m), B = Q-frag (col=n)
    f32x4 sacc[2][2];
#pragma unroll
    for (int nt = 0; nt < 2; ++nt)
#pragma unroll
      for (int t2 = 0; t2 < 2; ++t2) sacc[nt][t2] = (f32x4){0.f, 0.f, 0.f, 0.f};
#pragma unroll
    for (int ko = 0; ko < 8; ++ko) {
      bf16x8 kfa = *(const bf16x8*)
          &ktb[(((size_t)mt0 * 8 + ko) * 16 + c16) * 32 + g * 8];
      bf16x8 kfb = *(const bf16x8*)
          &ktb[(((size_t)(mt0 + 1) * 8 + ko) * 16 + c16) * 32 + g * 8];
#pragma unroll
      for (int nt = 0; nt < 2; ++nt) {
        sacc[nt][0] = __builtin_amdgcn_mfma_f32_16x16x32_bf16(
            kfa, qf[nt][ko], sacc[nt][0], 0, 0, 0);
        sacc[nt][1] = __builtin_amdgcn_mfma_f32_16x16x32_bf16(
            kfb, qf[nt][ko], sacc[nt][1], 0, 0, 0);
      }
    }

    // p = exp(s); packed b64 writes into wave-private ps rows; sum -> lrun
#pragma unroll
    for (int nt = 0; nt < 2; ++nt) {
      float rs = 0.f;
#pragma unroll
      for (int t2 = 0; t2 < 2; ++t2) {
        short4t pb;
#pragma unroll
        for (int r = 0; r < 4; ++r) {
          float p = __expf(sacc[nt][t2][r]);
          rs += p;
          pb[r] = f2bf(p);
        }
        *(short4t*)&ps[w * 32 + nt * 16 + c16][t2 * 16 + g * 4] = pb;
      }
      rs += __shfl_xor(rs, 16);
      rs += __shfl_xor(rs, 32);
      lrun[nt] += rs;
    }
    bf16x8 pf[2];
#pragma unroll
    for (int nt = 0; nt < 2; ++nt)
      pf[nt] = *(const bf16x8*)&ps[w * 32 + nt * 16 + c16][g * 8];

    // O += V P^T : A = V-frag direct from vt, B = P
    const size_t mt32 = (size_t)(mbase >> 5) + mi;
#pragma unroll
    for (int ot = 0; ot < 16; ++ot) {
      bf16x8 vf = *(const bf16x8*)&vtb[(mt32 * 256 + ot * 16 + c16) * 32 + g * 8];
#pragma unroll
      for (int nt = 0; nt < 2; ++nt)
        oacc[ot][nt] = __builtin_amdgcn_mfma_f32_16x16x32_bf16(
            vf, pf[nt], oacc[ot][nt], 0, 0, 0);
    }
  }

  // epilogue: accumulate unnormalized O and row sums (col=n layout)
  if (g == 0)
#pragma unroll
    for (int nt = 0; nt < 2; ++nt)
      atomicAdd(&lp[(b << 12) + n0 + w * 32 + nt * 16 + c16], lrun[nt]);

#pragma unroll
  for (int ot = 0; ot < 16; ++ot)
#pragma unroll
    for (int nt = 0; nt < 2; ++nt) {
      const int n = n0 + w * 32 + nt * 16 + c16;
      float* op = out + (size_t)b * O_ * N_ + (size_t)(ot * 16 + g * 4) * N_ + n;
#pragma unroll
      for (int r = 0; r < 4; ++r)
        atomicAdd(op + (size_t)r * N_, oacc[ot][nt][r]);
    }
}

// ---------------------------------------------------------------------------
extern "C" void kernel_launch(void* const* d_in, const int* in_sizes, int n_in,
                              void* d_out, int out_size, void* d_ws,
                              size_t ws_size, hipStream_t stream) {
  const float* x  = (const float*)d_in[0];
  const float* xx = (const float*)d_in[1];
  const float* Wq = (const float*)d_in[2];
  const float* Wk = (const float*)d_in[3];
  const float* Wv = (const float*)d_in[4];
  float* out = (float*)d_out;

  short* qg = (short*)d_ws;                         // 8.39 MB
  short* kt = qg + (size_t)B_ * N_ * O_;            // 8.39 MB (tiled K)
  short* vt = kt + (size_t)B_ * N_ * O_;            // 8.39 MB (tiled V)
  float* lp = (float*)(vt + (size_t)B_ * N_ * O_);  // 64 KB
  short* wb = (short*)(lp + B_ * N_);               // 384 KB

  wcvt<<<768, 256, 0, stream>>>(Wq, Wk, Wv, wb);
  zero_k<<<4112, 256, 0, stream>>>((float4*)out, (float4*)lp);
  qkv_proj<<<dim3(N_ / 64, B_, 3), 256, 0, stream>>>(x, xx, wb, qg, kt, vt);
  flash_attn<<<dim3(32, B_, SPLIT), 256, 0, stream>>>(qg, kt, vt, out, lp);
  norm_k<<<4096, 256, 0, stream>>>(out, lp);
}

// Round 6
// 219.910 us; speedup vs baseline: 1.6583x; 1.6583x over previous
//
#include <hip/hip_runtime.h>
#include <hip/hip_bf16.h>

// CrossAttention: B=4, C=256, N=4096, OUT=256, temp=16.
// v6: async-pipelined flash (m97 mechanism) + rebuilt proj.
//  - kt/vt stored in MFMA-fragment-tiled, XOR-swizzled layouts so
//    global_load_lds (16B, lane-contiguous, no padding possible) lands tiles
//    verbatim in LDS AND fragment ds_read_b128 is 2-way-bank (free, m136):
//      kt: [b][m>>4][o>>5][m&15][chunk g^((m>>1)&3)][8]
//      vt: [b][m>>5][o][chunk gm^(((o&15)>>1)&3)][8]
//  - flash: double-buffered K, single-buffered V, DMA for i+1 issued before
//    compute of i; 2 barriers/iter whose vmcnt-drain is covered by compute.
//  - proj: coalesced LDS transpose of x/xx; z=1 WG computes K AND V from one
//    staged xx tile (xx read once from HBM).
//  - No-max softmax (|logit|<=~2.5) -> split-m partials are sums, atomicAdd.
// Workspace: qg 8.4MB + kt 8.4MB + vt 8.4MB + lp 64KB + wb 384KB.

typedef __attribute__((ext_vector_type(8))) short bf16x8;
typedef __attribute__((ext_vector_type(4))) float f32x4;
typedef __attribute__((ext_vector_type(4))) short short4t;

constexpr int B_ = 4;
constexpr int C_ = 256;
constexpr int N_ = 4096;
constexpr int O_ = 256;
constexpr float INV_TEMP = 1.0f / 16.0f;
constexpr int SPLIT = 4;
constexpr int MCHUNK = N_ / SPLIT;   // 1024 keys per WG
constexpr int NITER = MCHUNK / 32;   // 32 iters of 32 keys

__device__ __forceinline__ short f2bf(float f) {
  union { float f; unsigned u; } v; v.f = f;
  unsigned r = v.u + 0x7fffu + ((v.u >> 16) & 1u);   // RNE
  return (short)(r >> 16);
}

// async global->LDS DMA, 16B per lane; LDS dst = wave-uniform base + lane*16
__device__ __forceinline__ void dma16(const short* g, short* l) {
  __builtin_amdgcn_global_load_lds(
      (const __attribute__((address_space(1))) unsigned int*)g,
      (__attribute__((address_space(3))) unsigned int*)l, 16, 0, 0);
}

// ---------------------------------------------------------------------------
__global__ void wcvt(const float* __restrict__ Wq, const float* __restrict__ Wk,
                     const float* __restrict__ Wv, short* __restrict__ wb) {
  int i = blockIdx.x * 256 + threadIdx.x;        // 0..196607
  int mat = i >> 16, off = i & 65535;
  const float* W = (mat == 0) ? Wq : (mat == 1 ? Wk : Wv);
  wb[i] = f2bf(W[off]);
}

__global__ void zero_k(float4* __restrict__ out4, float4* __restrict__ lp4) {
  int i = blockIdx.x * 256 + threadIdx.x;        // 0..1052671
  if (i < 1048576) out4[i] = (float4){0.f, 0.f, 0.f, 0.f};
  else lp4[i - 1048576] = (float4){0.f, 0.f, 0.f, 0.f};
}

__global__ void norm_k(float* __restrict__ out, const float* __restrict__ lp) {
  int i = blockIdx.x * 256 + threadIdx.x;        // float4 index
  int e = i * 4;
  int n = e & (N_ - 1);
  int b = e >> 20;
  float4 o = ((float4*)out)[i];
  const float4 l = *(const float4*)&lp[(b << 12) + n];
  o.x /= l.x; o.y /= l.y; o.z /= l.z; o.w /= l.w;
  ((float4*)out)[i] = o;
}

// ---------------------------------------------------------------------------
// 64x64 GEMM slice per wave from staged x-tile + global bf16 W.
// ---------------------------------------------------------------------------
__device__ __forceinline__ void gemm64(const short* __restrict__ W,
                                       const short (*xs)[264], int w, int g,
                                       int c16, f32x4 acc[4][4]) {
#pragma unroll
  for (int i = 0; i < 4; ++i)
#pragma unroll
    for (int j = 0; j < 4; ++j) acc[i][j] = (f32x4){0.f, 0.f, 0.f, 0.f};
#pragma unroll
  for (int ko = 0; ko < 8; ++ko) {
    bf16x8 afr[4], bfr[4];
#pragma unroll
    for (int ot = 0; ot < 4; ++ot)
      afr[ot] = *(const bf16x8*)&W[(w * 64 + ot * 16 + c16) * C_ + ko * 32 + g * 8];
#pragma unroll
    for (int nt = 0; nt < 4; ++nt)
      bfr[nt] = *(const bf16x8*)&xs[nt * 16 + c16][ko * 32 + g * 8];
#pragma unroll
    for (int ot = 0; ot < 4; ++ot)
#pragma unroll
      for (int nt = 0; nt < 4; ++nt)
        acc[ot][nt] = __builtin_amdgcn_mfma_f32_16x16x32_bf16(
            afr[ot], bfr[nt], acc[ot][nt], 0, 0, 0);
  }
}

// ---------------------------------------------------------------------------
// Projections. Grid (64, B, 2). Block 256 (4 waves).
// z=0: Q from x -> qg[b][n][o]/16.  z=1: K,V from xx (tile staged once).
// ---------------------------------------------------------------------------
__global__ __launch_bounds__(256, 2) void qkv_proj(
    const float* __restrict__ x, const float* __restrict__ xx,
    const short* __restrict__ wb,
    short* __restrict__ qg, short* __restrict__ kt, short* __restrict__ vt) {
  const int n0  = blockIdx.x * 64;
  const int b   = blockIdx.y;
  const int mat = blockIdx.z;
  const float* src = (mat == 0) ? x : xx;
  const int tid = threadIdx.x;
  const int w = tid >> 6, lane = tid & 63;
  const int g = lane >> 4, c16 = lane & 15;

  __shared__ short xs[64][264];   // staged tile, [n][c], rows 528B (2-way ok)

  {  // transpose staging: coalesced dword loads along n, short4 LDS writes
    const int n = tid & 63, cq = tid >> 6;
    const float* sp = src + (size_t)b * C_ * N_ + n0 + n;
#pragma unroll
    for (int rep = 0; rep < 16; ++rep) {
      int c = rep * 16 + cq * 4;
      short4t s4;
#pragma unroll
      for (int j = 0; j < 4; ++j) s4[j] = f2bf(sp[(size_t)(c + j) * N_]);
      *(short4t*)&xs[n][c] = s4;
    }
  }
  __syncthreads();

  f32x4 acc[4][4];
  if (mat == 0) {
    gemm64(wb, &xs[0], w, g, c16, acc);
    short* dst = qg + (size_t)b * N_ * O_;
#pragma unroll
    for (int ot = 0; ot < 4; ++ot)
#pragma unroll
      for (int nt = 0; nt < 4; ++nt) {
        int n = n0 + nt * 16 + c16;
        int o = w * 64 + ot * 16 + g * 4;
        short4t s;
        s[0] = f2bf(acc[ot][nt][0] * INV_TEMP);
        s[1] = f2bf(acc[ot][nt][1] * INV_TEMP);
        s[2] = f2bf(acc[ot][nt][2] * INV_TEMP);
        s[3] = f2bf(acc[ot][nt][3] * INV_TEMP);
        *(short4t*)(dst + (size_t)n * O_ + o) = s;
      }
  } else {
    // ---- K ----
    gemm64(wb + 65536, &xs[0], w, g, c16, acc);
#pragma unroll
    for (int ot = 0; ot < 4; ++ot)
#pragma unroll
      for (int nt = 0; nt < 4; ++nt) {
        int m = n0 + nt * 16 + c16;
        int o0 = w * 64 + ot * 16 + g * 4;
        int koo = o0 >> 5;
        int pos = ((o0 & 31) >> 3) ^ ((c16 >> 1) & 3);
        size_t base =
            (((size_t)(b * 256 + (m >> 4)) * 8 + koo) * 16 + c16) * 32 +
            pos * 8 + (g & 1) * 4;
        short4t s;
        s[0] = f2bf(acc[ot][nt][0]);
        s[1] = f2bf(acc[ot][nt][1]);
        s[2] = f2bf(acc[ot][nt][2]);
        s[3] = f2bf(acc[ot][nt][3]);
        *(short4t*)(kt + base) = s;
      }
    // ---- V ----
    gemm64(wb + 131072, &xs[0], w, g, c16, acc);
#pragma unroll
    for (int ot = 0; ot < 4; ++ot)
#pragma unroll
      for (int nt = 0; nt < 4; ++nt) {
        int m = n0 + nt * 16 + c16;
        size_t rowb = (size_t)(b * 128 + (m >> 5)) * 256;
        int gqm = (m & 31) >> 3, e = m & 7;
        int o0 = w * 64 + ot * 16 + g * 4;
#pragma unroll
        for (int r = 0; r < 4; ++r) {
          int o = o0 + r;
          int pos = gqm ^ (((o & 15) >> 1) & 3);
          vt[(rowb + o) * 32 + pos * 8 + e] = f2bf(acc[ot][nt][r]);
        }
      }
  }
}

// ---------------------------------------------------------------------------
// Flash (no-rescale) attention, async-pipelined. Grid (32, B, SPLIT).
// Block 256 (4 waves); wave w owns q-rows [w*32, w*32+32) of a 128-row block.
// Per 32-key iter: prefetch V(i) + K(i+1) via global_load_lds; S^T = K Q^T
// (32 MFMA) from kb[cur]; exp -> wave-private ps; barrier (drains V DMA);
// O += V P^T (32 MFMA) from vb; barrier (frees buffers). LDS 58KB -> 2 WG/CU.
// ---------------------------------------------------------------------------
__global__ __launch_bounds__(256, 2) void flash_attn(
    const short* __restrict__ qg, const short* __restrict__ kt,
    const short* __restrict__ vt, float* __restrict__ out,
    float* __restrict__ lp) {
  const int n0 = blockIdx.x * 128;
  const int b  = blockIdx.y;
  const int mbase = blockIdx.z * MCHUNK;
  const int tid = threadIdx.x;
  const int w = tid >> 6, lane = tid & 63;
  const int g = lane >> 4, c16 = lane & 15;

  __shared__ short kb[2][8192];    // K tiles (2x 32 keys x 256 o), 32 KB
  __shared__ short vb[8192];       // V tile (32 m x 256 o), 16 KB
  __shared__ short ps[128][40];    // P round-trip, wave-private rows, 10 KB

  const short* ktb = kt + (size_t)b * N_ * O_;
  const short* vtb = vt + (size_t)b * N_ * O_;

  // Q fragments: 2 n-subtiles x 8 k-steps (B-operand: col=n, k=o)
  bf16x8 qf[2][8];
#pragma unroll
  for (int nt = 0; nt < 2; ++nt) {
    const short* qrow =
        qg + (size_t)(b * N_ + n0 + w * 32 + nt * 16 + c16) * O_ + g * 8;
#pragma unroll
    for (int ko = 0; ko < 8; ++ko) qf[nt][ko] = *(const bf16x8*)(qrow + ko * 32);
  }

  f32x4 oacc[16][2];
#pragma unroll
  for (int i = 0; i < 16; ++i)
#pragma unroll
    for (int nt = 0; nt < 2; ++nt) oacc[i][nt] = (f32x4){0.f, 0.f, 0.f, 0.f};
  float lrun[2] = {0.f, 0.f};

  {  // prologue: K(0) -> kb[0]
    const short* src = ktb + (size_t)(mbase >> 4) * 4096;
#pragma unroll
    for (int j = 0; j < 4; ++j)
      dma16(src + (w * 4 + j) * 512 + lane * 8, &kb[0][(w * 4 + j) * 512]);
  }
  __syncthreads();

  const int sw = (g ^ ((c16 >> 1) & 3)) * 8;   // swizzled chunk offset (shorts)

  int cur = 0;
  for (int mi = 0; mi < NITER; ++mi) {
    {  // prefetch V(i) -> vb
      const short* src = vtb + ((size_t)(mbase >> 5) + mi) * 8192;
#pragma unroll
      for (int j = 0; j < 4; ++j)
        dma16(src + (w * 4 + j) * 512 + lane * 8, &vb[(w * 4 + j) * 512]);
    }
    if (mi + 1 < NITER) {  // prefetch K(i+1) -> kb[cur^1]
      const short* src = ktb + (size_t)((mbase >> 4) + (mi + 1) * 2) * 4096;
#pragma unroll
      for (int j = 0; j < 4; ++j)
        dma16(src + (w * 4 + j) * 512 + lane * 8, &kb[cur ^ 1][(w * 4 + j) * 512]);
    }

    // S^T = K Q^T : A = K-frag (row=m), B = Q-frag (col=n)
    f32x4 sacc[2][2];
#pragma unroll
    for (int nt = 0; nt < 2; ++nt)
#pragma unroll
      for (int t2 = 0; t2 < 2; ++t2) sacc[nt][t2] = (f32x4){0.f, 0.f, 0.f, 0.f};
#pragma unroll
    for (int ko = 0; ko < 8; ++ko) {
      const int ra = (ko * 16 + c16) * 32 + sw;
      bf16x8 kfa = *(const bf16x8*)&kb[cur][ra];
      bf16x8 kfb = *(const bf16x8*)&kb[cur][4096 + ra];
#pragma unroll
      for (int nt = 0; nt < 2; ++nt) {
        sacc[nt][0] = __builtin_amdgcn_mfma_f32_16x16x32_bf16(
            kfa, qf[nt][ko], sacc[nt][0], 0, 0, 0);
        sacc[nt][1] = __builtin_amdgcn_mfma_f32_16x16x32_bf16(
            kfb, qf[nt][ko], sacc[nt][1], 0, 0, 0);
      }
    }

    // p = exp(s) (no max subtraction: |s| <= ~2.5); wave-private ps rows
#pragma unroll
    for (int nt = 0; nt < 2; ++nt) {
      float rs = 0.f;
#pragma unroll
      for (int t2 = 0; t2 < 2; ++t2) {
        short4t pb;
#pragma unroll
        for (int r = 0; r < 4; ++r) {
          float p = __expf(sacc[nt][t2][r]);
          rs += p;
          pb[r] = f2bf(p);
        }
        *(short4t*)&ps[w * 32 + nt * 16 + c16][t2 * 16 + g * 4] = pb;
      }
      rs += __shfl_xor(rs, 16);
      rs += __shfl_xor(rs, 32);
      lrun[nt] += rs;
    }

    __syncthreads();   // drains V(i) DMA (vmcnt) + all waves' ps ready

    // O += V P^T : A = V-frag (row=o), B = P-frag (col=n)
    bf16x8 pf[2];
#pragma unroll
    for (int nt = 0; nt < 2; ++nt)
      pf[nt] = *(const bf16x8*)&ps[w * 32 + nt * 16 + c16][g * 8];
#pragma unroll
    for (int ot = 0; ot < 16; ++ot) {
      bf16x8 vf = *(const bf16x8*)&vb[(ot * 16 + c16) * 32 + sw];
#pragma unroll
      for (int nt = 0; nt < 2; ++nt)
        oacc[ot][nt] = __builtin_amdgcn_mfma_f32_16x16x32_bf16(
            vf, pf[nt], oacc[ot][nt], 0, 0, 0);
    }

    __syncthreads();   // frees vb and kb[cur] for next iter's prefetch
    cur ^= 1;
  }

  // epilogue: accumulate unnormalized O and row sums (col=n layout)
  if (g == 0)
#pragma unroll
    for (int nt = 0; nt < 2; ++nt)
      atomicAdd(&lp[(b << 12) + n0 + w * 32 + nt * 16 + c16], lrun[nt]);

#pragma unroll
  for (int ot = 0; ot < 16; ++ot)
#pragma unroll
    for (int nt = 0; nt < 2; ++nt) {
      const int n = n0 + w * 32 + nt * 16 + c16;
      float* op = out + (size_t)b * O_ * N_ + (size_t)(ot * 16 + g * 4) * N_ + n;
#pragma unroll
      for (int r = 0; r < 4; ++r)
        atomicAdd(op + (size_t)r * N_, oacc[ot][nt][r]);
    }
}

// ---------------------------------------------------------------------------
extern "C" void kernel_launch(void* const* d_in, const int* in_sizes, int n_in,
                              void* d_out, int out_size, void* d_ws,
                              size_t ws_size, hipStream_t stream) {
  const float* x  = (const float*)d_in[0];
  const float* xx = (const float*)d_in[1];
  const float* Wq = (const float*)d_in[2];
  const float* Wk = (const float*)d_in[3];
  const float* Wv = (const float*)d_in[4];
  float* out = (float*)d_out;

  short* qg = (short*)d_ws;                         // 8.39 MB
  short* kt = qg + (size_t)B_ * N_ * O_;            // 8.39 MB (tiled K)
  short* vt = kt + (size_t)B_ * N_ * O_;            // 8.39 MB (tiled V)
  float* lp = (float*)(vt + (size_t)B_ * N_ * O_);  // 64 KB
  short* wb = (short*)(lp + B_ * N_);               // 384 KB

  wcvt<<<768, 256, 0, stream>>>(Wq, Wk, Wv, wb);
  zero_k<<<4112, 256, 0, stream>>>((float4*)out, (float4*)lp);
  qkv_proj<<<dim3(N_ / 64, B_, 2), 256, 0, stream>>>(x, xx, wb, qg, kt, vt);
  flash_attn<<<dim3(32, B_, SPLIT), 256, 0, stream>>>(qg, kt, vt, out, lp);
  norm_k<<<4096, 256, 0, stream>>>(out, lp);
}

// Round 7
// 209.224 us; speedup vs baseline: 1.7430x; 1.0511x over previous
//
#include <hip/hip_runtime.h>
#include <hip/hip_bf16.h>

// CrossAttention: B=4, C=256, N=4096, OUT=256, temp=16.
// v7: m-split/o-split flash + packed V writes in proj.
//  - flash WG = 64 q-rows shared by 4 waves; per 64-key iter wave w computes
//    S for its own 16-key granule (K tile read ONCE) and PV for its own 64-o
//    slice (V tile read ONCE). ps (64n x 64m) is the only cross-wave LDS.
//    K/V LDS slices wave-private; 2 barriers per 64 keys. SPLIT=2, 2 WG/CU.
//  - DMA: V(i) issued at iter top (covered by S), K(i+1) after barB (covered
//    by PV); slices land via global_load_lds identity copy.
//  - proj: V gemm uses swapped MFMA operands (A=x, B=W) so D rows = m ->
//    packed b64 stores (kills the 2B global scatter); vt layout
//    [b][m>>6][o][chunk ((m&63)>>3)^(o&7)][m&7].
//  - No-max softmax (|logit|<=~2.5): split-m partials are sums, atomicAdd.
// Workspace: qg 8.4MB + kt 8.4MB + vt 8.4MB + lp 64KB + wb 384KB.

typedef __attribute__((ext_vector_type(8))) short bf16x8;
typedef __attribute__((ext_vector_type(4))) float f32x4;
typedef __attribute__((ext_vector_type(4))) short short4t;

constexpr int B_ = 4;
constexpr int C_ = 256;
constexpr int N_ = 4096;
constexpr int O_ = 256;
constexpr float INV_TEMP = 1.0f / 16.0f;
constexpr int SPLIT = 2;
constexpr int MCHUNK = N_ / SPLIT;     // 2048 keys per WG
constexpr int NITER = MCHUNK / 64;     // 32 iters of 64 keys

__device__ __forceinline__ short f2bf(float f) {
  union { float f; unsigned u; } v; v.f = f;
  unsigned r = v.u + 0x7fffu + ((v.u >> 16) & 1u);   // RNE
  return (short)(r >> 16);
}

// async global->LDS DMA: one call moves 64 lanes x 16B = 1024B (512 shorts)
__device__ __forceinline__ void dma16(const short* g, short* l) {
  __builtin_amdgcn_global_load_lds(
      (const __attribute__((address_space(1))) unsigned int*)g,
      (__attribute__((address_space(3))) unsigned int*)l, 16, 0, 0);
}

// ---------------------------------------------------------------------------
__global__ void wcvt(const float* __restrict__ Wq, const float* __restrict__ Wk,
                     const float* __restrict__ Wv, short* __restrict__ wb) {
  int i = blockIdx.x * 256 + threadIdx.x;        // 0..196607
  int mat = i >> 16, off = i & 65535;
  const float* W = (mat == 0) ? Wq : (mat == 1 ? Wk : Wv);
  wb[i] = f2bf(W[off]);
}

__global__ void zero_k(float4* __restrict__ out4, float4* __restrict__ lp4) {
  int i = blockIdx.x * 256 + threadIdx.x;        // 0..1052671
  if (i < 1048576) out4[i] = (float4){0.f, 0.f, 0.f, 0.f};
  else lp4[i - 1048576] = (float4){0.f, 0.f, 0.f, 0.f};
}

__global__ void norm_k(float* __restrict__ out, const float* __restrict__ lp) {
  int i = blockIdx.x * 256 + threadIdx.x;        // float4 index
  int e = i * 4;
  int n = e & (N_ - 1);
  int b = e >> 20;
  float4 o = ((float4*)out)[i];
  const float4 l = *(const float4*)&lp[(b << 12) + n];
  o.x /= l.x; o.y /= l.y; o.z /= l.z; o.w /= l.w;
  ((float4*)out)[i] = o;
}

// ---------------------------------------------------------------------------
// Projections. Grid (64, B, 3). Block 256 (4 waves). z: 0=Q, 1=K, 2=V.
// ---------------------------------------------------------------------------
__global__ __launch_bounds__(256, 2) void qkv_proj(
    const float* __restrict__ x, const float* __restrict__ xx,
    const short* __restrict__ wb,
    short* __restrict__ qg, short* __restrict__ kt, short* __restrict__ vt) {
  const int n0  = blockIdx.x * 64;
  const int b   = blockIdx.y;
  const int mat = blockIdx.z;
  const float* src = (mat == 0) ? x : xx;
  const short* W   = wb + mat * 65536;
  const int tid = threadIdx.x;
  const int w = tid >> 6, lane = tid & 63;
  const int g = lane >> 4, c16 = lane & 15;

  __shared__ short xs[64][264];   // staged tile [n][c], rows 528B

  {  // transpose staging: coalesced dword loads along n, short4 LDS writes
    const int n = tid & 63, cq = tid >> 6;
    const float* sp = src + (size_t)b * C_ * N_ + n0 + n;
#pragma unroll
    for (int rep = 0; rep < 16; ++rep) {
      int c = rep * 16 + cq * 4;
      short4t s4;
#pragma unroll
      for (int j = 0; j < 4; ++j) s4[j] = f2bf(sp[(size_t)(c + j) * N_]);
      *(short4t*)&xs[n][c] = s4;
    }
  }
  __syncthreads();

  f32x4 acc[4][4];
#pragma unroll
  for (int i = 0; i < 4; ++i)
#pragma unroll
    for (int j = 0; j < 4; ++j) acc[i][j] = (f32x4){0.f, 0.f, 0.f, 0.f};

#pragma unroll
  for (int ko = 0; ko < 8; ++ko) {
    bf16x8 wfr[4], xfr[4];
#pragma unroll
    for (int ot = 0; ot < 4; ++ot)
      wfr[ot] = *(const bf16x8*)&W[(w * 64 + ot * 16 + c16) * C_ + ko * 32 + g * 8];
#pragma unroll
    for (int nt = 0; nt < 4; ++nt)
      xfr[nt] = *(const bf16x8*)&xs[nt * 16 + c16][ko * 32 + g * 8];
    if (mat < 2) {
#pragma unroll
      for (int ot = 0; ot < 4; ++ot)
#pragma unroll
        for (int nt = 0; nt < 4; ++nt)
          acc[ot][nt] = __builtin_amdgcn_mfma_f32_16x16x32_bf16(
              wfr[ot], xfr[nt], acc[ot][nt], 0, 0, 0);
    } else {  // V: swapped operands -> D rows = m, cols = o
#pragma unroll
      for (int mt = 0; mt < 4; ++mt)
#pragma unroll
        for (int ot = 0; ot < 4; ++ot)
          acc[mt][ot] = __builtin_amdgcn_mfma_f32_16x16x32_bf16(
              xfr[mt], wfr[ot], acc[mt][ot], 0, 0, 0);
    }
  }

  if (mat == 0) {
    short* dst = qg + (size_t)b * N_ * O_;
#pragma unroll
    for (int ot = 0; ot < 4; ++ot)
#pragma unroll
      for (int nt = 0; nt < 4; ++nt) {
        int n = n0 + nt * 16 + c16;
        int o = w * 64 + ot * 16 + g * 4;
        short4t s;
        s[0] = f2bf(acc[ot][nt][0] * INV_TEMP);
        s[1] = f2bf(acc[ot][nt][1] * INV_TEMP);
        s[2] = f2bf(acc[ot][nt][2] * INV_TEMP);
        s[3] = f2bf(acc[ot][nt][3] * INV_TEMP);
        *(short4t*)(dst + (size_t)n * O_ + o) = s;
      }
  } else if (mat == 1) {
#pragma unroll
    for (int ot = 0; ot < 4; ++ot)
#pragma unroll
      for (int nt = 0; nt < 4; ++nt) {
        int m = n0 + nt * 16 + c16;
        int o0 = w * 64 + ot * 16 + g * 4;
        int koo = o0 >> 5;
        int pos = ((o0 & 31) >> 3) ^ ((c16 >> 1) & 3);
        size_t base =
            (((size_t)(b * 256 + (m >> 4)) * 8 + koo) * 16 + c16) * 32 +
            pos * 8 + (g & 1) * 4;
        short4t s;
        s[0] = f2bf(acc[ot][nt][0]);
        s[1] = f2bf(acc[ot][nt][1]);
        s[2] = f2bf(acc[ot][nt][2]);
        s[3] = f2bf(acc[ot][nt][3]);
        *(short4t*)(kt + base) = s;
      }
  } else {  // V: acc[mt][ot], rows m = mt*16+g*4+r, cols o = w*64+ot*16+c16
#pragma unroll
    for (int mt = 0; mt < 4; ++mt)
#pragma unroll
      for (int ot = 0; ot < 4; ++ot) {
        int o = w * 64 + ot * 16 + c16;
        int mloc = mt * 16 + g * 4;             // m within 64-tile
        int chunk = mloc >> 3;                  // = mt*2 + (g>>1)
        int pos = chunk ^ (o & 7);
        size_t base =
            ((size_t)(b * 64 + (n0 >> 6)) * 256 + o) * 64 + pos * 8 + (g & 1) * 4;
        short4t s;
        s[0] = f2bf(acc[mt][ot][0]);
        s[1] = f2bf(acc[mt][ot][1]);
        s[2] = f2bf(acc[mt][ot][2]);
        s[3] = f2bf(acc[mt][ot][3]);
        *(short4t*)(vt + base) = s;
      }
  }
}

// ---------------------------------------------------------------------------
// Flash (no-rescale) attention. Grid (64, B, SPLIT). Block 256 (4 waves).
// WG owns 64 q-rows shared by all waves (qf[4][8]). Per 64-key iter:
//   wave w: S^T for its 16-key granule (K slice wave-private in kb),
//   exp -> ps (shared), barB, PV for its 64-o slice (V slice wave-private).
// LDS: kb 32KB + vb 32KB + ps 9KB = 74.75KB -> 2 WG/CU.
// ---------------------------------------------------------------------------
__global__ __launch_bounds__(256, 2) void flash_attn(
    const short* __restrict__ qg, const short* __restrict__ kt,
    const short* __restrict__ vt, float* __restrict__ out,
    float* __restrict__ lp) {
  const int n0 = blockIdx.x * 64;
  const int b  = blockIdx.y;
  const int mbase = blockIdx.z * MCHUNK;
  const int tid = threadIdx.x;
  const int w = tid >> 6, lane = tid & 63;
  const int g = lane >> 4, c16 = lane & 15;

  __shared__ short kb[16384];      // 4 granules x 8KB (wave-private slices)
  __shared__ short vb[16384];      // 256 o x 64 m (wave-private o-slices)
  __shared__ short ps[64][72];     // P (64 n x 64 m), cross-wave

  const short* ktb = kt + (size_t)b * N_ * O_;
  const short* vtb = vt + (size_t)b * N_ * O_;

  // Q fragments for all 64 n (same in every wave; L1-broadcast)
  bf16x8 qf[4][8];
#pragma unroll
  for (int nt = 0; nt < 4; ++nt) {
    const short* qrow =
        qg + (size_t)(b * N_ + n0 + nt * 16 + c16) * O_ + g * 8;
#pragma unroll
    for (int ko = 0; ko < 8; ++ko) qf[nt][ko] = *(const bf16x8*)(qrow + ko * 32);
  }

  f32x4 oacc[4][4];    // [ot o-slice][nt]
#pragma unroll
  for (int i = 0; i < 4; ++i)
#pragma unroll
    for (int j = 0; j < 4; ++j) oacc[i][j] = (f32x4){0.f, 0.f, 0.f, 0.f};
  float lrun[4] = {0.f, 0.f, 0.f, 0.f};   // per-nt partial (this lane's m's)

  {  // prologue: K(0) granule w -> kb slice w
    const short* src = ktb + ((size_t)(mbase >> 4) + w) * 4096;
#pragma unroll
    for (int j = 0; j < 8; ++j)
      dma16(src + j * 512 + lane * 8, &kb[w * 4096 + j * 512]);
  }
  __syncthreads();

  const int sw = (g ^ ((c16 >> 1) & 3)) * 8;   // K chunk swizzle (shorts)

  for (int mi = 0; mi < NITER; ++mi) {
    {  // V(mi) -> vb (wave w loads its own o-slice rows w*64..w*64+63)
      const short* src = vtb + ((size_t)(mbase >> 6) + mi) * 16384 + w * 4096;
#pragma unroll
      for (int j = 0; j < 8; ++j)
        dma16(src + j * 512 + lane * 8, &vb[w * 4096 + j * 512]);
    }

    // S^T = K Q^T for granule w: A = K-frag (16 m), B = Q-frag (4 n-tiles)
    f32x4 sacc[4];
#pragma unroll
    for (int nt = 0; nt < 4; ++nt) sacc[nt] = (f32x4){0.f, 0.f, 0.f, 0.f};
#pragma unroll
    for (int ko = 0; ko < 8; ++ko) {
      bf16x8 kf = *(const bf16x8*)&kb[w * 4096 + (ko * 16 + c16) * 32 + sw];
#pragma unroll
      for (int nt = 0; nt < 4; ++nt)
        sacc[nt] = __builtin_amdgcn_mfma_f32_16x16x32_bf16(
            kf, qf[nt][ko], sacc[nt], 0, 0, 0);
    }

    // p = exp(s); lane holds m = w*16+g*4+r, n = nt*16+c16
#pragma unroll
    for (int nt = 0; nt < 4; ++nt) {
      short4t pb;
      float rs = 0.f;
#pragma unroll
      for (int r = 0; r < 4; ++r) {
        float p = __expf(sacc[nt][r]);
        rs += p;
        pb[r] = f2bf(p);
      }
      lrun[nt] += rs;
      *(short4t*)&ps[nt * 16 + c16][w * 16 + g * 4] = pb;
    }

    __syncthreads();   // barB: ps visible; kb S-reads done; vb(mi) drained

    if (mi + 1 < NITER) {  // K(mi+1) granule w -> kb slice w (covered by PV)
      const short* src =
          ktb + ((size_t)(mbase >> 4) + (mi + 1) * 4 + w) * 4096;
#pragma unroll
      for (int j = 0; j < 8; ++j)
        dma16(src + j * 512 + lane * 8, &kb[w * 4096 + j * 512]);
    }

    // O += V P^T for o-slice w: A = V-frag, B = P-frag
#pragma unroll
    for (int kk = 0; kk < 2; ++kk) {
      bf16x8 pf[4];
#pragma unroll
      for (int nt = 0; nt < 4; ++nt)
        pf[nt] = *(const bf16x8*)&ps[nt * 16 + c16][kk * 32 + g * 8];
#pragma unroll
      for (int ot = 0; ot < 4; ++ot) {
        int pos = (kk * 4 + g) ^ (c16 & 7);
        bf16x8 vf =
            *(const bf16x8*)&vb[(w * 64 + ot * 16 + c16) * 64 + pos * 8];
#pragma unroll
        for (int nt = 0; nt < 4; ++nt)
          oacc[ot][nt] = __builtin_amdgcn_mfma_f32_16x16x32_bf16(
              vf, pf[nt], oacc[ot][nt], 0, 0, 0);
      }
    }

    __syncthreads();   // barA: vb/ps PV-reads done; kb(mi+1) drained
  }

  // l partials: fold over g (each lane then holds sum over wave's m-slices)
#pragma unroll
  for (int nt = 0; nt < 4; ++nt) {
    float v = lrun[nt];
    v += __shfl_xor(v, 16);
    v += __shfl_xor(v, 32);
    if (lane < 16) atomicAdd(&lp[(b << 12) + n0 + nt * 16 + lane], v);
  }

  // unnormalized O: o = w*64+ot*16+g*4+r, n = n0+nt*16+c16
#pragma unroll
  for (int ot = 0; ot < 4; ++ot)
#pragma unroll
    for (int nt = 0; nt < 4; ++nt) {
      const int n = n0 + nt * 16 + c16;
      float* op = out + (size_t)b * O_ * N_ +
                  (size_t)(w * 64 + ot * 16 + g * 4) * N_ + n;
#pragma unroll
      for (int r = 0; r < 4; ++r)
        atomicAdd(op + (size_t)r * N_, oacc[ot][nt][r]);
    }
}

// ---------------------------------------------------------------------------
extern "C" void kernel_launch(void* const* d_in, const int* in_sizes, int n_in,
                              void* d_out, int out_size, void* d_ws,
                              size_t ws_size, hipStream_t stream) {
  const float* x  = (const float*)d_in[0];
  const float* xx = (const float*)d_in[1];
  const float* Wq = (const float*)d_in[2];
  const float* Wk = (const float*)d_in[3];
  const float* Wv = (const float*)d_in[4];
  float* out = (float*)d_out;

  short* qg = (short*)d_ws;                         // 8.39 MB
  short* kt = qg + (size_t)B_ * N_ * O_;            // 8.39 MB (tiled K)
  short* vt = kt + (size_t)B_ * N_ * O_;            // 8.39 MB (tiled V)
  float* lp = (float*)(vt + (size_t)B_ * N_ * O_);  // 64 KB
  short* wb = (short*)(lp + B_ * N_);               // 384 KB

  wcvt<<<768, 256, 0, stream>>>(Wq, Wk, Wv, wb);
  zero_k<<<4112, 256, 0, stream>>>((float4*)out, (float4*)lp);
  qkv_proj<<<dim3(N_ / 64, B_, 3), 256, 0, stream>>>(x, xx, wb, qg, kt, vt);
  flash_attn<<<dim3(64, B_, SPLIT), 256, 0, stream>>>(qg, kt, vt, out, lp);
  norm_k<<<4096, 256, 0, stream>>>(out, lp);
}

// Round 8
// 207.289 us; speedup vs baseline: 1.7592x; 1.0093x over previous
//
#include <hip/hip_runtime.h>
#include <hip/hip_bf16.h>

// CrossAttention: B=4, C=256, N=4096, OUT=256, temp=16.
// v8: producer/consumer wave specialization, SPLIT=1, coalesced proj stores.
//  - flash: 512-thr WG (4 producer + 4 consumer waves), 64 q-rows, 64-key
//    intervals. Producers: S for own 16-key granule (K DMA dbuf, Q in regs),
//    exp -> ps dbuf. Consumers: PV(i-1) for own 64-o slice (V DMA dbuf).
//    One barrier/interval; S/PV/exp/DMA overlap on every SIMD (1P+1C).
//    SPLIT=1 => in-kernel normalize, direct stores, no atomics/zero/norm.
//    Grid (8,32): x -> XCD, b = x>>1 => per-XCD L2 holds one batch's K/V.
//  - proj: unchanged math; epilogue now assembles each mat's contiguous
//    32KB output span in LDS, then blasts 16B/lane coalesced stores
//    (kills the 8B-scatter write amplification suspected of ~70us).
// Workspace: qg 8.4MB + kt 8.4MB + vt 8.4MB + wb 384KB.

typedef __attribute__((ext_vector_type(8))) short bf16x8;
typedef __attribute__((ext_vector_type(4))) float f32x4;
typedef __attribute__((ext_vector_type(4))) short short4t;

constexpr int B_ = 4;
constexpr int C_ = 256;
constexpr int N_ = 4096;
constexpr int O_ = 256;
constexpr float INV_TEMP = 1.0f / 16.0f;
constexpr int NIT = 64;   // 64-key blocks per WG (all 4096 keys, SPLIT=1)

__device__ __forceinline__ short f2bf(float f) {
  union { float f; unsigned u; } v; v.f = f;
  unsigned r = v.u + 0x7fffu + ((v.u >> 16) & 1u);   // RNE
  return (short)(r >> 16);
}

// async global->LDS DMA: one call moves 64 lanes x 16B = 1024B (512 shorts)
__device__ __forceinline__ void dma16(const short* g, short* l) {
  __builtin_amdgcn_global_load_lds(
      (const __attribute__((address_space(1))) unsigned int*)g,
      (__attribute__((address_space(3))) unsigned int*)l, 16, 0, 0);
}

// ---------------------------------------------------------------------------
__global__ void wcvt(const float* __restrict__ Wq, const float* __restrict__ Wk,
                     const float* __restrict__ Wv, short* __restrict__ wb) {
  int i = blockIdx.x * 256 + threadIdx.x;        // 0..196607
  int mat = i >> 16, off = i & 65535;
  const float* W = (mat == 0) ? Wq : (mat == 1 ? Wk : Wv);
  wb[i] = f2bf(W[off]);
}

// ---------------------------------------------------------------------------
// Projections. Grid (64, B, 3). Block 256 (4 waves). z: 0=Q, 1=K, 2=V.
// Epilogue: assemble the WG's contiguous 32KB output span in LDS, blast out.
// ---------------------------------------------------------------------------
__global__ __launch_bounds__(256, 2) void qkv_proj(
    const float* __restrict__ x, const float* __restrict__ xx,
    const short* __restrict__ wb,
    short* __restrict__ qg, short* __restrict__ kt, short* __restrict__ vt) {
  const int n0  = blockIdx.x * 64;
  const int b   = blockIdx.y;
  const int mat = blockIdx.z;
  const float* src = (mat == 0) ? x : xx;
  const short* W   = wb + mat * 65536;
  const int tid = threadIdx.x;
  const int w = tid >> 6, lane = tid & 63;
  const int g = lane >> 4, c16 = lane & 15;

  __shared__ __align__(16) short xs[64][264];   // staged tile / out assembly

  {  // transpose staging: coalesced dword loads along n, short4 LDS writes
    const int n = tid & 63, cq = tid >> 6;
    const float* sp = src + (size_t)b * C_ * N_ + n0 + n;
#pragma unroll
    for (int rep = 0; rep < 16; ++rep) {
      int c = rep * 16 + cq * 4;
      short4t s4;
#pragma unroll
      for (int j = 0; j < 4; ++j) s4[j] = f2bf(sp[(size_t)(c + j) * N_]);
      *(short4t*)&xs[n][c] = s4;
    }
  }
  __syncthreads();

  f32x4 acc[4][4];
#pragma unroll
  for (int i = 0; i < 4; ++i)
#pragma unroll
    for (int j = 0; j < 4; ++j) acc[i][j] = (f32x4){0.f, 0.f, 0.f, 0.f};

#pragma unroll
  for (int ko = 0; ko < 8; ++ko) {
    bf16x8 wfr[4], xfr[4];
#pragma unroll
    for (int ot = 0; ot < 4; ++ot)
      wfr[ot] = *(const bf16x8*)&W[(w * 64 + ot * 16 + c16) * C_ + ko * 32 + g * 8];
#pragma unroll
    for (int nt = 0; nt < 4; ++nt)
      xfr[nt] = *(const bf16x8*)&xs[nt * 16 + c16][ko * 32 + g * 8];
    if (mat < 2) {
#pragma unroll
      for (int ot = 0; ot < 4; ++ot)
#pragma unroll
        for (int nt = 0; nt < 4; ++nt)
          acc[ot][nt] = __builtin_amdgcn_mfma_f32_16x16x32_bf16(
              wfr[ot], xfr[nt], acc[ot][nt], 0, 0, 0);
    } else {  // V: swapped operands -> D rows = m, cols = o
#pragma unroll
      for (int mt = 0; mt < 4; ++mt)
#pragma unroll
        for (int ot = 0; ot < 4; ++ot)
          acc[mt][ot] = __builtin_amdgcn_mfma_f32_16x16x32_bf16(
              xfr[mt], wfr[ot], acc[mt][ot], 0, 0, 0);
    }
  }

  __syncthreads();               // xs tile reads done; reuse as out-assembly
  short* ob = &xs[0][0];         // 16384 shorts used

  if (mat == 0) {
#pragma unroll
    for (int ot = 0; ot < 4; ++ot)
#pragma unroll
      for (int nt = 0; nt < 4; ++nt) {
        int f = (nt * 16 + c16) * 256 + w * 64 + ot * 16 + g * 4;
        short4t s;
        s[0] = f2bf(acc[ot][nt][0] * INV_TEMP);
        s[1] = f2bf(acc[ot][nt][1] * INV_TEMP);
        s[2] = f2bf(acc[ot][nt][2] * INV_TEMP);
        s[3] = f2bf(acc[ot][nt][3] * INV_TEMP);
        *(short4t*)&ob[f] = s;
      }
  } else if (mat == 1) {
#pragma unroll
    for (int ot = 0; ot < 4; ++ot)
#pragma unroll
      for (int nt = 0; nt < 4; ++nt) {
        int koo = w * 2 + (ot >> 1);
        int pos = (((ot & 1) * 2 + (g >> 1)) ^ ((c16 >> 1) & 3));
        int f = nt * 4096 + koo * 512 + c16 * 32 + pos * 8 + (g & 1) * 4;
        short4t s;
        s[0] = f2bf(acc[ot][nt][0]);
        s[1] = f2bf(acc[ot][nt][1]);
        s[2] = f2bf(acc[ot][nt][2]);
        s[3] = f2bf(acc[ot][nt][3]);
        *(short4t*)&ob[f] = s;
      }
  } else {  // V: acc[mt][ot], rows m = mt*16+g*4+r, cols o = w*64+ot*16+c16
#pragma unroll
    for (int mt = 0; mt < 4; ++mt)
#pragma unroll
      for (int ot = 0; ot < 4; ++ot) {
        int o = w * 64 + ot * 16 + c16;
        int pos = (mt * 2 + (g >> 1)) ^ (o & 7);
        int f = o * 64 + pos * 8 + (g & 1) * 4;
        short4t s;
        s[0] = f2bf(acc[mt][ot][0]);
        s[1] = f2bf(acc[mt][ot][1]);
        s[2] = f2bf(acc[mt][ot][2]);
        s[3] = f2bf(acc[mt][ot][3]);
        *(short4t*)&ob[f] = s;
      }
  }
  __syncthreads();

  short* dst = (mat == 0) ? qg + ((size_t)b * N_ + n0) * O_
             : (mat == 1) ? kt + (size_t)(b * 256 + (n0 >> 4)) * 4096
                          : vt + (size_t)(b * 64 + (n0 >> 6)) * 16384;
  const uint4* s4 = (const uint4*)ob;
  uint4* d4 = (uint4*)dst;
#pragma unroll
  for (int j = 0; j < 8; ++j) d4[j * 256 + tid] = s4[j * 256 + tid];
}

// ---------------------------------------------------------------------------
// Flash attention, wave-specialized. Grid (8, 32). Block 512 (8 waves).
// b = x>>1 (XCD-pinned), nblk = (x&1)*32 + y, n0 = nblk*64.
// Waves 0-3 producers (16-key granules), 4-7 consumers (64-o slices).
// LDS: kb 2x32KB + vb 2x32KB + ps 2x9.2KB + lsum = 147.4KB -> 1 WG/CU.
// ---------------------------------------------------------------------------
__global__ __launch_bounds__(512, 2) void flash_attn(
    const short* __restrict__ qg, const short* __restrict__ kt,
    const short* __restrict__ vt, float* __restrict__ out) {
  const int xg = blockIdx.x;
  const int b  = xg >> 1;
  const int n0 = (((xg & 1) << 5) + blockIdx.y) * 64;
  const int tid = threadIdx.x;
  const int w = tid >> 6, lane = tid & 63;
  const int g = lane >> 4, c16 = lane & 15;
  const bool prod = (w < 4);
  const int pw = w & 3;            // producer granule / consumer o-slice

  __shared__ short kb[2][16384];   // K dbuf: 64 keys x 256 o
  __shared__ short vb[2][16384];   // V dbuf: 64 m x 256 o (o-major rows)
  __shared__ short ps[2][64][72];  // P dbuf: 64 n x 64 m
  __shared__ float lsum[4][64];

  const short* ktb = kt + (size_t)b * N_ * O_;
  const short* vtb = vt + (size_t)b * N_ * O_;

  bf16x8 qf[4][8];
  float lrun[4] = {0.f, 0.f, 0.f, 0.f};
  f32x4 oacc[4][4];
#pragma unroll
  for (int i = 0; i < 4; ++i)
#pragma unroll
    for (int j = 0; j < 4; ++j) oacc[i][j] = (f32x4){0.f, 0.f, 0.f, 0.f};

  if (prod) {
    // Q fragments: 4 n-subtiles x 8 k-steps (B-operand: col=n, k=o)
#pragma unroll
    for (int nt = 0; nt < 4; ++nt) {
      const short* qrow =
          qg + (size_t)(b * N_ + n0 + nt * 16 + c16) * O_ + g * 8;
#pragma unroll
      for (int ko = 0; ko < 8; ++ko)
        qf[nt][ko] = *(const bf16x8*)(qrow + ko * 32);
    }
    // prologue: K(0) granule pw
    const short* src = ktb + (size_t)pw * 4096;
#pragma unroll
    for (int j = 0; j < 8; ++j)
      dma16(src + j * 512 + lane * 8, &kb[0][pw * 4096 + j * 512]);
  }
  __syncthreads();

  const int sw = (g ^ ((c16 >> 1) & 3)) * 8;   // K chunk swizzle (shorts)

  for (int i = 0; i <= NIT; ++i) {
    if (prod) {
      if (i < NIT) {
        if (i + 1 < NIT) {  // prefetch K(i+1) granule pw
          const short* src = ktb + (size_t)(4 * (i + 1) + pw) * 4096;
          short* dst = &kb[(i + 1) & 1][pw * 4096];
#pragma unroll
          for (int j = 0; j < 8; ++j)
            dma16(src + j * 512 + lane * 8, dst + j * 512);
        }
        // S^T = K Q^T for granule pw (rows m), all 64 n
        const short* ksl = &kb[i & 1][pw * 4096];
        f32x4 sacc[4];
#pragma unroll
        for (int nt = 0; nt < 4; ++nt) sacc[nt] = (f32x4){0.f, 0.f, 0.f, 0.f};
#pragma unroll
        for (int ko = 0; ko < 8; ++ko) {
          bf16x8 kf = *(const bf16x8*)&ksl[(ko * 16 + c16) * 32 + sw];
#pragma unroll
          for (int nt = 0; nt < 4; ++nt)
            sacc[nt] = __builtin_amdgcn_mfma_f32_16x16x32_bf16(
                kf, qf[nt][ko], sacc[nt], 0, 0, 0);
        }
        // p = exp(s) (no max subtraction: |s| <= ~2.5 by construction)
#pragma unroll
        for (int nt = 0; nt < 4; ++nt) {
          short4t pb;
          float rs = 0.f;
#pragma unroll
          for (int r = 0; r < 4; ++r) {
            float p = __expf(sacc[nt][r]);
            rs += p;
            pb[r] = f2bf(p);
          }
          lrun[nt] += rs;   // lane-local; folded over g at epilogue
          *(short4t*)&ps[i & 1][nt * 16 + c16][pw * 16 + g * 4] = pb;
        }
      }
    } else {
      if (i < NIT) {  // prefetch V(i) o-slice pw
        const short* src = vtb + (size_t)i * 16384 + pw * 4096;
        short* dst = &vb[i & 1][pw * 4096];
#pragma unroll
        for (int j = 0; j < 8; ++j)
          dma16(src + j * 512 + lane * 8, dst + j * 512);
      }
      if (i > 0) {  // O += V(i-1) P(i-1)^T for o-slice pw
        const int pb_ = (i - 1) & 1;
#pragma unroll
        for (int kk = 0; kk < 2; ++kk) {
          bf16x8 pf[4];
#pragma unroll
          for (int nt = 0; nt < 4; ++nt)
            pf[nt] = *(const bf16x8*)&ps[pb_][nt * 16 + c16][kk * 32 + g * 8];
#pragma unroll
          for (int ot = 0; ot < 4; ++ot) {
            int pos = (kk * 4 + g) ^ (c16 & 7);
            bf16x8 vf = *(const bf16x8*)
                &vb[pb_][(pw * 64 + ot * 16 + c16) * 64 + pos * 8];
#pragma unroll
            for (int nt = 0; nt < 4; ++nt)
              oacc[ot][nt] = __builtin_amdgcn_mfma_f32_16x16x32_bf16(
                  vf, pf[nt], oacc[ot][nt], 0, 0, 0);
          }
        }
      }
    }
    __syncthreads();
  }

  // epilogue: producers publish granule row-sums; consumers normalize+store
  if (prod) {
#pragma unroll
    for (int nt = 0; nt < 4; ++nt) {
      float v = lrun[nt];
      v += __shfl_xor(v, 16);
      v += __shfl_xor(v, 32);
      if (lane < 16) lsum[pw][nt * 16 + lane] = v;
    }
  }
  __syncthreads();
  if (!prod) {
#pragma unroll
    for (int nt = 0; nt < 4; ++nt) {
      const int nl = nt * 16 + c16;
      float l = lsum[0][nl] + lsum[1][nl] + lsum[2][nl] + lsum[3][nl];
      float li = 1.0f / l;
#pragma unroll
      for (int ot = 0; ot < 4; ++ot) {
        float* op = out + ((size_t)b * O_ + pw * 64 + ot * 16 + g * 4) * N_ +
                    n0 + nl;
#pragma unroll
        for (int r = 0; r < 4; ++r)
          op[(size_t)r * N_] = oacc[ot][nt][r] * li;
      }
    }
  }
}

// ---------------------------------------------------------------------------
extern "C" void kernel_launch(void* const* d_in, const int* in_sizes, int n_in,
                              void* d_out, int out_size, void* d_ws,
                              size_t ws_size, hipStream_t stream) {
  const float* x  = (const float*)d_in[0];
  const float* xx = (const float*)d_in[1];
  const float* Wq = (const float*)d_in[2];
  const float* Wk = (const float*)d_in[3];
  const float* Wv = (const float*)d_in[4];
  float* out = (float*)d_out;

  short* qg = (short*)d_ws;                         // 8.39 MB
  short* kt = qg + (size_t)B_ * N_ * O_;            // 8.39 MB (tiled K)
  short* vt = kt + (size_t)B_ * N_ * O_;            // 8.39 MB (tiled V)
  short* wb = vt + (size_t)B_ * N_ * O_;            // 384 KB

  wcvt<<<768, 256, 0, stream>>>(Wq, Wk, Wv, wb);
  qkv_proj<<<dim3(N_ / 64, B_, 3), 256, 0, stream>>>(x, xx, wb, qg, kt, vt);
  flash_attn<<<dim3(8, 32), 512, 0, stream>>>(qg, kt, vt, out);
}